// Round 10
// baseline (91.421 us; speedup 1.0000x reference)
//
#include <hip/hip_runtime.h>
#include <math.h>

#define NUM_FREQS   64
#define NUM_BINS    128
#define NUM_QUERIES 32768
#define HEAD_DIM    128
#define EPS         1e-8f
#define NQB         32   // queries per block (4 waves x 8 j each)

typedef float v2f __attribute__((ext_vector_type(2)));

// ---- packed fp32 helpers: PLAIN FORM ONLY (no op_sel/neg modifiers) -------
__device__ __forceinline__ v2f pk_add(v2f a, v2f b) {
    v2f d;
    asm("v_pk_add_f32 %0, %1, %2" : "=v"(d) : "v"(a), "v"(b));
    return d;
}
__device__ __forceinline__ v2f pk_mul(v2f a, v2f b) {
    v2f d;
    asm("v_pk_mul_f32 %0, %1, %2" : "=v"(d) : "v"(a), "v"(b));
    return d;
}
__device__ __forceinline__ v2f pk_fma(v2f a, v2f b, v2f c) {
    v2f d;
    asm("v_pk_fma_f32 %0, %1, %2, %3" : "=v"(d) : "v"(a), "v"(b), "v"(c));
    return d;
}

// packed rsqrt initial guess: per-half int bithack (2 int ops per value)
__device__ __forceinline__ v2f pk_rsqrt_guess(v2f s) {
    int il = 0x5f375a86 - (__float_as_int(s.x) >> 1);
    int ih = 0x5f375a86 - (__float_as_int(s.y) >> 1);
    v2f r;
    r.x = __int_as_float(il);
    r.y = __int_as_float(ih);
    return r;
}

// one packed (q-pair, bin) slot:
// s = (Pr - qr)^2 + (Pi - qi)^2 + eps   [nqr/nqi are pre-negated]
// d = sqrt(s) via bithack + 1 Newton (all plain pk ops)
// acc += d*wz + qm*mw
__device__ __forceinline__ v2f slot(v2f prd, v2f pid, v2f wzd, v2f mwd,
                                    v2f nqr, v2f nqi, v2f qm2, v2f acc,
                                    v2f eps2, v2f nhalf, v2f c15) {
    v2f er = pk_add(prd, nqr);
    v2f ei = pk_add(pid, nqi);
    v2f t  = pk_fma(ei, ei, eps2);
    v2f s  = pk_fma(er, er, t);
    v2f r0 = pk_rsqrt_guess(s);
    v2f nxh = pk_mul(s, nhalf);          // -0.5 s
    v2f u   = pk_mul(nxh, r0);
    v2f w   = pk_fma(u, r0, c15);        // 1.5 - 0.5 s r0^2
    v2f r1  = pk_mul(r0, w);
    v2f d   = pk_mul(s, r1);             // s * rsqrt(s) = sqrt(s)
    v2f a   = pk_fma(qm2, mwd, acc);
    return pk_fma(d, wzd, a);
}

// ---------------------------------------------------------------------------
// Fused prep: blocks [0,128) normalize Q -> NEGATED planes Qnr/Qni + Qm;
// blocks [128,160) pack probe constants probe4[f*128+b] = {Pr, Pi, wz, mw}.
// ---------------------------------------------------------------------------
__global__ void prep_fused(const float* __restrict__ Q,
                           const float* __restrict__ rp,
                           const float* __restrict__ wraw,
                           const float* __restrict__ mw,
                           float* __restrict__ Qnr,
                           float* __restrict__ Qni,
                           float* __restrict__ Qm,
                           float4* __restrict__ probe4) {
    const int bid = blockIdx.x;
    const int tid = threadIdx.x;
    if (bid < 128) {
        int q = bid * 256 + tid;
        const float4* Qrow = reinterpret_cast<const float4*>(Q + (size_t)q * HEAD_DIM);
        float4 buf[32];
        float s = 0.0f;
        #pragma unroll
        for (int i = 0; i < 32; i++) {
            float4 v = Qrow[i];
            buf[i] = v;
            s = fmaf(v.x, v.x, fmaf(v.y, v.y, fmaf(v.z, v.z, fmaf(v.w, v.w, s))));
        }
        float inv = 1.0f / (__builtin_amdgcn_sqrtf(s) + EPS);
        #pragma unroll
        for (int i = 0; i < 16; i++) {
            float4 r  = buf[i];
            float4 im = buf[16 + i];
            float rr[4] = { r.x,  r.y,  r.z,  r.w  };
            float ii[4] = { im.x, im.y, im.z, im.w };
            #pragma unroll
            for (int k = 0; k < 4; k++) {
                float qr = rr[k] * inv;
                float qi = ii[k] * inv;
                float qm = __builtin_amdgcn_sqrtf(fmaf(qr, qr, fmaf(qi, qi, EPS)));
                int f = 4 * i + k;
                Qnr[(size_t)f * NUM_QUERIES + q] = -qr;   // negated!
                Qni[(size_t)f * NUM_QUERIES + q] = -qi;
                Qm [(size_t)f * NUM_QUERIES + q] = qm;
            }
        }
    } else {
        int idx = (bid - 128) * 256 + tid;       // idx = f*128 + b
        if (idx >= NUM_FREQS * NUM_BINS) return;
        int f = idx >> 7;
        int b = idx & 127;
        float pr = rp[b * HEAD_DIM + f];
        float pi = rp[b * HEAD_DIM + NUM_FREQS + f];
        float w  = wraw[b * NUM_FREQS + f];
        float sp = fmaxf(w, 0.0f) + log1pf(expf(-fabsf(w)));   // stable softplus
        float m  = mw[b * NUM_FREQS + f];
        probe4[idx] = make_float4(pr, pi, -sp, m);
    }
}

// ---------------------------------------------------------------------------
// Main: block = 256 threads (4 waves); block owns 32 queries; wave w owns
// j in [8w, 8w+8); lane covers bins (lane, lane+64). Queries are PAIRED into
// v2f lanes (j even/odd) so all packed operands are either pre-packed LDS
// pairs or loop-invariant probe duplicates. All VOP3P ops are plain-form.
// Grid = 1024 blocks = 4 blocks/CU co-resident (24 KB LDS each).
// ---------------------------------------------------------------------------
__global__ __launch_bounds__(256, 4) void main_kernel(
        const float4* __restrict__ probe4,
        const float*  __restrict__ Qnr,
        const float*  __restrict__ Qni,
        const float*  __restrict__ Qm,
        const float*  __restrict__ bias,
        float*        __restrict__ out) {
    __shared__ float snr[NUM_FREQS * NQB];   // 8 KB each plane
    __shared__ float sni[NUM_FREQS * NQB];
    __shared__ float sqm[NUM_FREQS * NQB];

    const int tid   = threadIdx.x;
    const int qbase = blockIdx.x * NQB;

    // Stage q-panel: 512 float4 per plane, 2 per thread, coalesced.
    #pragma unroll
    for (int i = 0; i < 2; i++) {
        int idx = i * 256 + tid;             // 0..511 = f*8 + j4
        int f = idx >> 3, j4 = idx & 7;
        const float4* gr = reinterpret_cast<const float4*>(Qnr + (size_t)f * NUM_QUERIES + qbase);
        const float4* gi = reinterpret_cast<const float4*>(Qni + (size_t)f * NUM_QUERIES + qbase);
        const float4* gm = reinterpret_cast<const float4*>(Qm  + (size_t)f * NUM_QUERIES + qbase);
        reinterpret_cast<float4*>(snr)[f * 8 + j4] = gr[j4];
        reinterpret_cast<float4*>(sni)[f * 8 + j4] = gi[j4];
        reinterpret_cast<float4*>(sqm)[f * 8 + j4] = gm[j4];
    }
    __syncthreads();

    const int lane = tid & 63;
    const int wave = tid >> 6;

    const v2f eps2  = { EPS, EPS };
    const v2f nhalf = { -0.5f, -0.5f };
    const v2f c15   = { 1.5f, 1.5f };

    v2f acc[4][2];
    #pragma unroll
    for (int p = 0; p < 4; p++) {
        acc[p][0] = (v2f){0.0f, 0.0f};
        acc[p][1] = (v2f){0.0f, 0.0f};
    }

    const float4* pp = probe4 + lane;                                  // +128/f
    const float4* ar = reinterpret_cast<const float4*>(snr) + wave * 2; // +8/f
    const float4* ai = reinterpret_cast<const float4*>(sni) + wave * 2;
    const float4* am = reinterpret_cast<const float4*>(sqm) + wave * 2;

    #pragma unroll 2
    for (int f = 0; f < NUM_FREQS; f++) {
        float4 P0 = pp[0];                   // bin = lane
        float4 P1 = pp[64];                  // bin = lane + 64
        float4 R0 = ar[0], R1 = ar[1];       // nqr j 0..7 (4 pairs)
        float4 I0 = ai[0], I1 = ai[1];       // nqi
        float4 M0 = am[0], M1 = am[1];       // qm
        pp += NUM_BINS; ar += 8; ai += 8; am += 8;

        // probe duplicates (loop-invariant over the 8 j's)
        v2f pr0 = {P0.x, P0.x}, pi0 = {P0.y, P0.y}, wz0 = {P0.z, P0.z}, mw0 = {P0.w, P0.w};
        v2f pr1 = {P1.x, P1.x}, pi1 = {P1.y, P1.y}, wz1 = {P1.z, P1.z}, mw1 = {P1.w, P1.w};

        const v2f nr[4] = { {R0.x, R0.y}, {R0.z, R0.w}, {R1.x, R1.y}, {R1.z, R1.w} };
        const v2f ni[4] = { {I0.x, I0.y}, {I0.z, I0.w}, {I1.x, I1.y}, {I1.z, I1.w} };
        const v2f qm2[4] = { {M0.x, M0.y}, {M0.z, M0.w}, {M1.x, M1.y}, {M1.z, M1.w} };

        #pragma unroll
        for (int p = 0; p < 4; p++) {
            acc[p][0] = slot(pr0, pi0, wz0, mw0, nr[p], ni[p], qm2[p], acc[p][0],
                             eps2, nhalf, c15);
            acc[p][1] = slot(pr1, pi1, wz1, mw1, nr[p], ni[p], qm2[p], acc[p][1],
                             eps2, nhalf, c15);
        }
    }

    const int jb = wave * 8;
    float b0 = bias[lane];
    float b1 = bias[64 + lane];
    #pragma unroll
    for (int p = 0; p < 4; p++) {
        size_t r0 = (size_t)(qbase + jb + 2 * p) * NUM_BINS;
        size_t r1 = r0 + NUM_BINS;
        out[r0 + lane]      = acc[p][0].x + b0;    // coalesced
        out[r1 + lane]      = acc[p][0].y + b0;
        out[r0 + 64 + lane] = acc[p][1].x + b1;
        out[r1 + 64 + lane] = acc[p][1].y + b1;
    }
}

// ---------------------------------------------------------------------------
// Fallback (only if ws_size is too small): fully self-contained, slower.
// ---------------------------------------------------------------------------
__global__ void fallback_kernel(const float* __restrict__ Q,
                                const float* __restrict__ rp,
                                const float* __restrict__ wraw,
                                const float* __restrict__ mw,
                                const float* __restrict__ bias,
                                float* __restrict__ out) {
    __shared__ float qn[HEAD_DIM];
    __shared__ float qmag[NUM_FREQS];
    __shared__ float red[NUM_BINS];
    const int t = threadIdx.x;
    const int q = blockIdx.x;

    float v = Q[(size_t)q * HEAD_DIM + t];
    red[t] = v * v;
    __syncthreads();
    for (int s = 64; s > 0; s >>= 1) {
        if (t < s) red[t] += red[t + s];
        __syncthreads();
    }
    float inv = 1.0f / (__builtin_amdgcn_sqrtf(red[0]) + EPS);
    qn[t] = v * inv;
    __syncthreads();
    if (t < NUM_FREQS) {
        float a = qn[t], c = qn[t + NUM_FREQS];
        qmag[t] = __builtin_amdgcn_sqrtf(fmaf(a, a, fmaf(c, c, EPS)));
    }
    __syncthreads();

    const int b = t;
    float acc = 0.0f;
    for (int f = 0; f < NUM_FREQS; f++) {
        float pr = rp[(size_t)b * HEAD_DIM + f];
        float pi = rp[(size_t)b * HEAD_DIM + NUM_FREQS + f];
        float w  = wraw[(size_t)b * NUM_FREQS + f];
        float ew = -(fmaxf(w, 0.0f) + log1pf(expf(-fabsf(w))));
        float er = pr - qn[f];
        float ei = pi - qn[f + NUM_FREQS];
        float d  = __builtin_amdgcn_sqrtf(fmaf(er, er, fmaf(ei, ei, EPS)));
        acc = fmaf(d, ew, fmaf(qmag[f], mw[(size_t)b * NUM_FREQS + f], acc));
    }
    out[(size_t)q * NUM_BINS + b] = acc + bias[b];
}

// ---------------------------------------------------------------------------
extern "C" void kernel_launch(void* const* d_in, const int* in_sizes, int n_in,
                              void* d_out, int out_size, void* d_ws, size_t ws_size,
                              hipStream_t stream) {
    const float* Q    = (const float*)d_in[0];
    const float* rp   = (const float*)d_in[1];
    const float* wraw = (const float*)d_in[2];
    const float* mw   = (const float*)d_in[3];
    const float* bias = (const float*)d_in[4];
    float* out = (float*)d_out;

    const size_t probeBytes = (size_t)NUM_FREQS * NUM_BINS * sizeof(float4);   // 128 KiB
    const size_t planeBytes = (size_t)NUM_FREQS * NUM_QUERIES * sizeof(float); // 8 MiB
    const size_t need       = probeBytes + 3 * planeBytes;                     // ~24.1 MiB

    if (ws_size >= need) {
        float4* probe4 = (float4*)d_ws;
        float*  Qnr    = (float*)((char*)d_ws + probeBytes);
        float*  Qni    = Qnr + (size_t)NUM_FREQS * NUM_QUERIES;
        float*  Qm     = Qni + (size_t)NUM_FREQS * NUM_QUERIES;

        hipLaunchKernelGGL(prep_fused, dim3(128 + 32), dim3(256), 0, stream,
                           Q, rp, wraw, mw, Qnr, Qni, Qm, probe4);
        hipLaunchKernelGGL(main_kernel, dim3(NUM_QUERIES / NQB), dim3(256), 0,
                           stream, probe4, Qnr, Qni, Qm, bias, out);
    } else {
        hipLaunchKernelGGL(fallback_kernel, dim3(NUM_QUERIES), dim3(NUM_BINS), 0,
                           stream, Q, rp, wraw, mw, bias, out);
    }
}

// Round 11
// 78.459 us; speedup vs baseline: 1.1652x; 1.1652x over previous
//
#include <hip/hip_runtime.h>
#include <math.h>

#define NUM_FREQS   64
#define NUM_BINS    128
#define NUM_QUERIES 32768
#define HEAD_DIM    128
#define EPS         1e-8f
#define NQB         16   // queries per block (4 waves x 4 j each)

// ---------------------------------------------------------------------------
// Fused prep: blocks [0,128) normalize Q -> Qri {qr,qi} + Qm planes;
// blocks [128,160) pack probe constants for the expanded-distance form:
//   probeA[f*128+b] = { -2*Pr, -2*Pi, Pr^2+Pi^2, -softplus(w) }
//   probeM[f*128+b] = mw
// (eps is carried inside qm^2 = qr^2+qi^2+eps, so C'' needs no eps.)
// ---------------------------------------------------------------------------
__global__ void prep_fused(const float* __restrict__ Q,
                           const float* __restrict__ rp,
                           const float* __restrict__ wraw,
                           const float* __restrict__ mw,
                           float2* __restrict__ Qri,
                           float*  __restrict__ Qm,
                           float4* __restrict__ probeA,
                           float*  __restrict__ probeM) {
    const int bid = blockIdx.x;
    const int tid = threadIdx.x;
    if (bid < 128) {
        int q = bid * 256 + tid;
        const float4* Qrow = reinterpret_cast<const float4*>(Q + (size_t)q * HEAD_DIM);
        float4 buf[32];
        float s = 0.0f;
        #pragma unroll
        for (int i = 0; i < 32; i++) {
            float4 v = Qrow[i];
            buf[i] = v;
            s = fmaf(v.x, v.x, fmaf(v.y, v.y, fmaf(v.z, v.z, fmaf(v.w, v.w, s))));
        }
        float inv = 1.0f / (__builtin_amdgcn_sqrtf(s) + EPS);
        #pragma unroll
        for (int i = 0; i < 16; i++) {
            float4 r  = buf[i];
            float4 im = buf[16 + i];
            float rr[4] = { r.x,  r.y,  r.z,  r.w  };
            float ii[4] = { im.x, im.y, im.z, im.w };
            #pragma unroll
            for (int k = 0; k < 4; k++) {
                float qr = rr[k] * inv;
                float qi = ii[k] * inv;
                float qm = __builtin_amdgcn_sqrtf(fmaf(qr, qr, fmaf(qi, qi, EPS)));
                int f = 4 * i + k;
                Qri[(size_t)f * NUM_QUERIES + q] = make_float2(qr, qi);  // coalesced
                Qm [(size_t)f * NUM_QUERIES + q] = qm;
            }
        }
    } else {
        int idx = (bid - 128) * 256 + tid;       // idx = f*128 + b
        if (idx >= NUM_FREQS * NUM_BINS) return;
        int f = idx >> 7;
        int b = idx & 127;
        float pr = rp[b * HEAD_DIM + f];
        float pi = rp[b * HEAD_DIM + NUM_FREQS + f];
        float w  = wraw[b * NUM_FREQS + f];
        float sp = fmaxf(w, 0.0f) + log1pf(expf(-fabsf(w)));   // stable softplus
        probeA[idx] = make_float4(-2.0f * pr, -2.0f * pi,
                                  fmaf(pr, pr, pi * pi), -sp);
        probeM[idx] = mw[b * NUM_FREQS + f];
    }
}

// ---------------------------------------------------------------------------
// Main: block = 256 threads (4 waves); block owns 16 queries; wave w owns
// j in [4w, 4w+4); lane covers bins (lane, lane+64) -> 8 outputs per lane.
// Expanded distance: s = C'' + qm^2 - 2Pr*qr - 2Pi*qi  (5 fma + 1 sqrt per
// output, incl. magnitude term). Grid = 2048 blocks = 8 blocks/CU, 12.5 KB
// LDS each -> 32 waves/CU (8/SIMD): TLP hides LDS/L2 latency, no SW pipeline.
// ---------------------------------------------------------------------------
__global__ __launch_bounds__(256, 8) void main_kernel(
        const float4* __restrict__ probeA,
        const float*  __restrict__ probeM,
        const float2* __restrict__ Qri,
        const float*  __restrict__ Qm,
        const float*  __restrict__ bias,
        float*        __restrict__ out) {
    __shared__ float2 sri[NUM_FREQS][NQB];   // 8 KB  [f][j] {qr,qi}
    __shared__ float  sqm[NUM_FREQS][NQB];   // 4 KB  [f][j] qm

    const int tid   = threadIdx.x;
    const int qbase = blockIdx.x * NQB;

    // Stage q-panel: 512 + 256 float4 stores, 3 per thread, coalesced.
    #pragma unroll
    for (int i = 0; i < 3; i++) {
        int idx = i * 256 + tid;
        if (idx < 512) {                       // sri: f = idx>>3, chunk = idx&7
            int f = idx >> 3, c = idx & 7;
            reinterpret_cast<float4*>(&sri[f][0])[c] =
                reinterpret_cast<const float4*>(Qri + (size_t)f * NUM_QUERIES + qbase)[c];
        } else {                               // sqm: f = t>>2, chunk = t&3
            int t2 = idx - 512;
            int f = t2 >> 2, c = t2 & 3;
            reinterpret_cast<float4*>(&sqm[f][0])[c] =
                reinterpret_cast<const float4*>(Qm + (size_t)f * NUM_QUERIES + qbase)[c];
        }
    }
    __syncthreads();

    const int lane = tid & 63;
    const int wave = tid >> 6;
    const int jb   = wave * 4;               // this wave's j-chunk base

    float acc0[4], acc1[4];
    #pragma unroll
    for (int p = 0; p < 4; p++) { acc0[p] = 0.0f; acc1[p] = 0.0f; }

    const float4* pA = probeA + lane;        // advances by 128 per f
    const float*  pM = probeM + lane;

    #pragma unroll 4
    for (int f = 0; f < NUM_FREQS; f++) {
        float4 P0 = pA[0];                   // {-2Pr, -2Pi, C'', wz}  bin = lane
        float4 P1 = pA[64];                  //                        bin = lane+64
        float  w0 = pM[0];
        float  w1 = pM[64];
        float4 r01 = *reinterpret_cast<const float4*>(&sri[f][jb]);      // j0,j1
        float4 r23 = *reinterpret_cast<const float4*>(&sri[f][jb + 2]);  // j2,j3
        float4 qm4 = *reinterpret_cast<const float4*>(&sqm[f][jb]);      // qm j0..3
        pA += NUM_BINS; pM += NUM_BINS;

        const float qrv[4] = { r01.x, r01.z, r23.x, r23.z };
        const float qiv[4] = { r01.y, r01.w, r23.y, r23.w };
        const float qmv[4] = { qm4.x, qm4.y, qm4.z, qm4.w };

        #pragma unroll
        for (int p = 0; p < 4; p++) {
            float qr = qrv[p], qi = qiv[p], qm = qmv[p];
            {   // bin = lane
                float a = fmaf(qm, qm, P0.z);
                a = fmaf(P0.x, qr, a);
                a = fmaf(P0.y, qi, a);
                float d = __builtin_amdgcn_sqrtf(a);
                acc0[p] = fmaf(d, P0.w, fmaf(qm, w0, acc0[p]));
            }
            {   // bin = lane + 64
                float a = fmaf(qm, qm, P1.z);
                a = fmaf(P1.x, qr, a);
                a = fmaf(P1.y, qi, a);
                float d = __builtin_amdgcn_sqrtf(a);
                acc1[p] = fmaf(d, P1.w, fmaf(qm, w1, acc1[p]));
            }
        }
    }

    float b0 = bias[lane];
    float b1 = bias[64 + lane];
    #pragma unroll
    for (int p = 0; p < 4; p++) {
        size_t row = (size_t)(qbase + jb + p) * NUM_BINS;
        out[row + lane]      = acc0[p] + b0;     // coalesced
        out[row + 64 + lane] = acc1[p] + b1;     // coalesced
    }
}

// ---------------------------------------------------------------------------
// Fallback (only if ws_size is too small): fully self-contained, slower.
// ---------------------------------------------------------------------------
__global__ void fallback_kernel(const float* __restrict__ Q,
                                const float* __restrict__ rp,
                                const float* __restrict__ wraw,
                                const float* __restrict__ mw,
                                const float* __restrict__ bias,
                                float* __restrict__ out) {
    __shared__ float qn[HEAD_DIM];
    __shared__ float qmag[NUM_FREQS];
    __shared__ float red[NUM_BINS];
    const int t = threadIdx.x;
    const int q = blockIdx.x;

    float v = Q[(size_t)q * HEAD_DIM + t];
    red[t] = v * v;
    __syncthreads();
    for (int s = 64; s > 0; s >>= 1) {
        if (t < s) red[t] += red[t + s];
        __syncthreads();
    }
    float inv = 1.0f / (__builtin_amdgcn_sqrtf(red[0]) + EPS);
    qn[t] = v * inv;
    __syncthreads();
    if (t < NUM_FREQS) {
        float a = qn[t], c = qn[t + NUM_FREQS];
        qmag[t] = __builtin_amdgcn_sqrtf(fmaf(a, a, fmaf(c, c, EPS)));
    }
    __syncthreads();

    const int b = t;
    float acc = 0.0f;
    for (int f = 0; f < NUM_FREQS; f++) {
        float pr = rp[(size_t)b * HEAD_DIM + f];
        float pi = rp[(size_t)b * HEAD_DIM + NUM_FREQS + f];
        float w  = wraw[(size_t)b * NUM_FREQS + f];
        float ew = -(fmaxf(w, 0.0f) + log1pf(expf(-fabsf(w))));
        float er = pr - qn[f];
        float ei = pi - qn[f + NUM_FREQS];
        float d  = __builtin_amdgcn_sqrtf(fmaf(er, er, fmaf(ei, ei, EPS)));
        acc = fmaf(d, ew, fmaf(qmag[f], mw[(size_t)b * NUM_FREQS + f], acc));
    }
    out[(size_t)q * NUM_BINS + b] = acc + bias[b];
}

// ---------------------------------------------------------------------------
extern "C" void kernel_launch(void* const* d_in, const int* in_sizes, int n_in,
                              void* d_out, int out_size, void* d_ws, size_t ws_size,
                              hipStream_t stream) {
    const float* Q    = (const float*)d_in[0];
    const float* rp   = (const float*)d_in[1];
    const float* wraw = (const float*)d_in[2];
    const float* mw   = (const float*)d_in[3];
    const float* bias = (const float*)d_in[4];
    float* out = (float*)d_out;

    const size_t pABytes  = (size_t)NUM_FREQS * NUM_BINS * sizeof(float4);    // 128 KiB
    const size_t pMBytes  = (size_t)NUM_FREQS * NUM_BINS * sizeof(float);     //  32 KiB
    const size_t qriBytes = (size_t)NUM_FREQS * NUM_QUERIES * sizeof(float2); //  16 MiB
    const size_t qmBytes  = (size_t)NUM_FREQS * NUM_QUERIES * sizeof(float);  //   8 MiB
    const size_t need     = pABytes + pMBytes + qriBytes + qmBytes;           // ~24.2 MiB

    if (ws_size >= need) {
        float4* probeA = (float4*)d_ws;
        float*  probeM = (float*)((char*)d_ws + pABytes);
        float2* Qri    = (float2*)((char*)d_ws + pABytes + pMBytes);
        float*  Qm     = (float*)((char*)d_ws + pABytes + pMBytes + qriBytes);

        hipLaunchKernelGGL(prep_fused, dim3(128 + 32), dim3(256), 0, stream,
                           Q, rp, wraw, mw, Qri, Qm, probeA, probeM);
        hipLaunchKernelGGL(main_kernel, dim3(NUM_QUERIES / NQB), dim3(256), 0,
                           stream, probeA, probeM, Qri, Qm, bias, out);
    } else {
        hipLaunchKernelGGL(fallback_kernel, dim3(NUM_QUERIES), dim3(NUM_BINS), 0,
                           stream, Q, rp, wraw, mw, bias, out);
    }
}